// Round 1
// baseline (268.064 us; speedup 1.0000x reference)
//
#include <hip/hip_runtime.h>
#include <hip/hip_bf16.h>

#define NB 4
#define CC 512
#define TT 4096
#define HH 8
#define DHH 64
#define C3 1536
#define NTC (NB*TT*CC)   // 8388608 elems per [N,T,C] tensor

typedef __attribute__((ext_vector_type(4))) float f32x4;
typedef __attribute__((ext_vector_type(8))) short short8;
typedef unsigned short ushort;

__device__ __forceinline__ ushort f2bf(float f){
    union { float f; unsigned u; } x; x.f = f;
    unsigned r = x.u + 0x7fffu + ((x.u >> 16) & 1u);   // RNE
    return (ushort)(r >> 16);
}

// ---------------- K0a: convert weights fp32 -> bf16 ----------------
// W_in: 1536x512 (196608 float4), W_out: 512x512 (65536 float4)
__global__ __launch_bounds__(256) void cvt_w(const float* __restrict__ Wi,
                                             const float* __restrict__ Wo,
                                             ushort* __restrict__ Wb,
                                             ushort* __restrict__ Wob){
    int t = blockIdx.x * 256 + threadIdx.x;   // 262144 threads total
    const float* src; ushort* dst; int idx;
    if (t < 196608){ src = Wi; dst = Wb;  idx = t; }
    else           { src = Wo; dst = Wob; idx = t - 196608; }
    f32x4 v = *((const f32x4*)src + idx);
    ushort4 o;
    o.x = f2bf(v[0]); o.y = f2bf(v[1]); o.z = f2bf(v[2]); o.w = f2bf(v[3]);
    *((ushort4*)dst + idx) = o;
}

// ---------------- K0b: transpose+cvt q/k/v [N,C,T] fp32 -> [N,T,C] bf16 ----------------
// grid: 3 * NB * (CC/64) * (TT/64) = 6144 blocks, 256 threads
__global__ __launch_bounds__(256) void transpose_cvt(const float* __restrict__ q,
                                                     const float* __restrict__ k,
                                                     const float* __restrict__ v,
                                                     ushort* __restrict__ XT){
    __shared__ float sT[64][65];   // [t][c], padded
    int b = blockIdx.x;
    int tch = b % 64;  b /= 64;
    int cch = b % 8;   b /= 8;
    int n   = b % 4;   b /= 4;
    int which = b;     // 0=q 1=k 2=v
    const float* src = (which == 0) ? q : (which == 1) ? k : v;
    const float* base = src + (size_t)n*CC*TT + (size_t)(cch*64)*TT + (size_t)tch*64;
    // read [c][t] coalesced, write LDS transposed [t][c]
    for (int i = 0; i < 4; ++i){
        int f = i*256 + threadIdx.x;
        int t4 = f & 15, c = f >> 4;
        f32x4 val = *(const f32x4*)(base + (size_t)c*TT + t4*4);
        for (int j = 0; j < 4; ++j) sT[t4*4 + j][c] = val[j];
    }
    __syncthreads();
    ushort* dst = XT + (size_t)which*NTC + ((size_t)n*TT + (size_t)tch*64)*CC + cch*64;
    for (int i = 0; i < 4; ++i){
        int f = i*256 + threadIdx.x;
        int c4 = f & 15, t = f >> 4;
        ushort4 o;
        o.x = f2bf(sT[t][c4*4+0]); o.y = f2bf(sT[t][c4*4+1]);
        o.z = f2bf(sT[t][c4*4+2]); o.w = f2bf(sT[t][c4*4+3]);
        *(ushort4*)(dst + (size_t)t*CC + c4*4) = o;
    }
}

// ---------------- K1: packed QKV projection GEMM ----------------
// P[m=n*T+t][co 0..1536) = sum_ci XT_sel[m][ci] * Wb[co][ci] + b_in[co]
// grid (12, 128): x = co-tile, y = m-tile; 256 threads
__global__ __launch_bounds__(256) void proj_gemm(const ushort* __restrict__ XT,
                                                 const ushort* __restrict__ Wb,
                                                 const float* __restrict__ b_in,
                                                 ushort* __restrict__ P){
    __shared__ ushort sA[128][72];
    __shared__ ushort sB[128][72];
    const int tid = threadIdx.x;
    const int co0 = blockIdx.x * 128;
    const int m0  = blockIdx.y * 128;
    const int which = co0 >> 9;            // 0:q 1:k 2:v
    const ushort* Abase = XT + (size_t)which*NTC + (size_t)m0*CC;
    const ushort* Bbase = Wb + (size_t)co0*CC;
    const int w = tid >> 6, lane = tid & 63;
    const int wr = w >> 1, wc = w & 1;
    const int l15 = lane & 15, quad = lane >> 4;
    f32x4 acc[4][4] = {};
    for (int kb = 0; kb < 8; ++kb){
        __syncthreads();
        for (int i = 0; i < 4; ++i){
            int f = i*256 + tid;
            int r = f >> 3, c8 = f & 7;
            *(int4*)&sA[r][c8*8] = *(const int4*)(Abase + (size_t)r*CC + kb*64 + c8*8);
            *(int4*)&sB[r][c8*8] = *(const int4*)(Bbase + (size_t)r*CC + kb*64 + c8*8);
        }
        __syncthreads();
        for (int ks = 0; ks < 2; ++ks){
            short8 aF[4], bF[4];
            for (int mi = 0; mi < 4; ++mi)
                aF[mi] = *(const short8*)&sA[wr*64 + mi*16 + l15][ks*32 + quad*8];
            for (int ni = 0; ni < 4; ++ni)
                bF[ni] = *(const short8*)&sB[wc*64 + ni*16 + l15][ks*32 + quad*8];
            for (int mi = 0; mi < 4; ++mi)
                for (int ni = 0; ni < 4; ++ni)
                    acc[mi][ni] = __builtin_amdgcn_mfma_f32_16x16x32_bf16(
                        aF[mi], bF[ni], acc[mi][ni], 0, 0, 0);
        }
    }
    float bj[4];
    for (int ni = 0; ni < 4; ++ni) bj[ni] = b_in[co0 + wc*64 + ni*16 + l15];
    for (int mi = 0; mi < 4; ++mi){
        int m = m0 + wr*64 + mi*16 + quad*4;
        for (int ni = 0; ni < 4; ++ni){
            int co = co0 + wc*64 + ni*16 + l15;
            ushort* dst = P + (size_t)m*C3 + co;
            for (int r = 0; r < 4; ++r)
                dst[(size_t)r*C3] = f2bf(acc[mi][ni][r] + bj[ni]);
        }
    }
}

// ---------------- K2: per-(n,chunk,head) attention ----------------
// grid 2048 blocks (n*64*8 + ch*8 + h), 256 threads = 4 waves; each wave owns 16 q-rows
__global__ __launch_bounds__(256) void attn_kernel(const ushort* __restrict__ P,
                                                   const float* __restrict__ masks,
                                                   ushort* __restrict__ ctx){
    __shared__ ushort sQ[64][72], sK[64][72], sVt[64][72], sP[64][72];
    int bid = blockIdx.x;
    int h = bid & 7, ch = (bid >> 3) & 63, n = bid >> 9;
    const int tid = threadIdx.x, lane = tid & 63, w = tid >> 6;
    const int l15 = lane & 15, quad = lane >> 4;
    const size_t rowbase = (size_t)n*TT + (size_t)ch*64;
    for (int i = 0; i < 2; ++i){
        int f = i*256 + tid;
        int r = f >> 3, c8 = f & 7;
        const ushort* src = P + (rowbase + r)*C3 + h*64 + c8*8;
        *(int4*)&sQ[r][c8*8] = *(const int4*)(src);
        *(int4*)&sK[r][c8*8] = *(const int4*)(src + 512);
        int4 vv = *(const int4*)(src + 1024);
        const ushort* pv = (const ushort*)&vv;
        for (int j = 0; j < 8; ++j) sVt[c8*8 + j][r] = pv[j];  // V transposed: [d][kp]
    }
    __syncthreads();
    const int m0w = w*16;
    // S = Q K^T (wave's 16 rows x 64 cols)
    short8 aQ[2]; f32x4 accS[4] = {};
    for (int ks = 0; ks < 2; ++ks)
        aQ[ks] = *(const short8*)&sQ[m0w + l15][ks*32 + quad*8];
    for (int ni = 0; ni < 4; ++ni)
        for (int ks = 0; ks < 2; ++ks){
            short8 bK = *(const short8*)&sK[ni*16 + l15][ks*32 + quad*8];
            accS[ni] = __builtin_amdgcn_mfma_f32_16x16x32_bf16(aQ[ks], bK, accS[ni], 0,0,0);
        }
    // softmax over 64 key cols; row r lives on 16 lanes of this quad, reg r
    float madd[4];
    for (int ni = 0; ni < 4; ++ni){
        float mv = masks[(size_t)n*TT + ch*64 + ni*16 + l15];
        madd[ni] = (mv > 0.f) ? 0.f : -1e9f;
    }
    float s[4][4];
    for (int ni = 0; ni < 4; ++ni)
        for (int r = 0; r < 4; ++r) s[ni][r] = accS[ni][r]*0.125f + madd[ni];
    float ex[4][4];
    for (int r = 0; r < 4; ++r){
        float m1 = fmaxf(fmaxf(s[0][r], s[1][r]), fmaxf(s[2][r], s[3][r]));
        for (int d = 1; d < 16; d <<= 1) m1 = fmaxf(m1, __shfl_xor(m1, d));
        float a = 0.f;
        for (int ni = 0; ni < 4; ++ni){ float e = __expf(s[ni][r] - m1); ex[ni][r] = e; a += e; }
        for (int d = 1; d < 16; d <<= 1) a += __shfl_xor(a, d);
        float rs = 1.0f / a;
        for (int ni = 0; ni < 4; ++ni)
            sP[m0w + quad*4 + r][ni*16 + l15] = f2bf(ex[ni][r] * rs);
    }
    // O = P V   (sP rows are wave-private; sVt written before barrier)
    short8 aP[2]; f32x4 accO[4] = {};
    for (int ks = 0; ks < 2; ++ks)
        aP[ks] = *(const short8*)&sP[m0w + l15][ks*32 + quad*8];
    for (int ni = 0; ni < 4; ++ni)
        for (int ks = 0; ks < 2; ++ks){
            short8 bV = *(const short8*)&sVt[ni*16 + l15][ks*32 + quad*8];
            accO[ni] = __builtin_amdgcn_mfma_f32_16x16x32_bf16(aP[ks], bV, accO[ni], 0,0,0);
        }
    for (int ni = 0; ni < 4; ++ni)
        for (int r = 0; r < 4; ++r){
            size_t row = rowbase + m0w + quad*4 + r;
            ctx[row*CC + h*64 + ni*16 + l15] = f2bf(accO[ni][r]);
        }
}

// ---------------- K3: out-projection + bias + mask + residual, transposed store ----------------
// out_pre[n][co][t] = (sum_ci ctx[m][ci]*Wob[co][ci] + b_out[co]) * mask[n][t] + x[n][co][t]
// grid (4, 128); D-layout gives 4 consecutive t per lane -> coalesced float4 stores
__global__ __launch_bounds__(256) void out_gemm(const ushort* __restrict__ ctx,
                                                const ushort* __restrict__ Wob,
                                                const float* __restrict__ b_out,
                                                const float* __restrict__ x,
                                                const float* __restrict__ masks,
                                                float* __restrict__ out){
    __shared__ ushort sA[128][72];
    __shared__ ushort sB[128][72];
    const int tid = threadIdx.x;
    const int co0 = blockIdx.x * 128;
    const int m0  = blockIdx.y * 128;
    const int n = m0 >> 12, t0 = m0 & 4095;
    const ushort* Abase = ctx + (size_t)m0*CC;
    const ushort* Bbase = Wob + (size_t)co0*CC;
    const int w = tid >> 6, lane = tid & 63;
    const int wr = w >> 1, wc = w & 1;
    const int l15 = lane & 15, quad = lane >> 4;
    f32x4 acc[4][4] = {};
    for (int kb = 0; kb < 8; ++kb){
        __syncthreads();
        for (int i = 0; i < 4; ++i){
            int f = i*256 + tid;
            int r = f >> 3, c8 = f & 7;
            *(int4*)&sA[r][c8*8] = *(const int4*)(Abase + (size_t)r*CC + kb*64 + c8*8);
            *(int4*)&sB[r][c8*8] = *(const int4*)(Bbase + (size_t)r*CC + kb*64 + c8*8);
        }
        __syncthreads();
        for (int ks = 0; ks < 2; ++ks){
            short8 aF[4], bF[4];
            for (int mi = 0; mi < 4; ++mi)
                aF[mi] = *(const short8*)&sA[wr*64 + mi*16 + l15][ks*32 + quad*8];
            for (int ni = 0; ni < 4; ++ni)
                bF[ni] = *(const short8*)&sB[wc*64 + ni*16 + l15][ks*32 + quad*8];
            for (int mi = 0; mi < 4; ++mi)
                for (int ni = 0; ni < 4; ++ni)
                    acc[mi][ni] = __builtin_amdgcn_mfma_f32_16x16x32_bf16(
                        aF[mi], bF[ni], acc[mi][ni], 0, 0, 0);
        }
    }
    float bo[4];
    for (int ni = 0; ni < 4; ++ni) bo[ni] = b_out[co0 + wc*64 + ni*16 + l15];
    for (int mi = 0; mi < 4; ++mi){
        int t = t0 + wr*64 + mi*16 + quad*4;
        f32x4 mk = *(const f32x4*)(masks + (size_t)n*TT + t);
        for (int ni = 0; ni < 4; ++ni){
            int co = co0 + wc*64 + ni*16 + l15;
            const f32x4 xv = *(const f32x4*)(x + ((size_t)n*CC + co)*TT + t);
            f32x4 o;
            for (int r = 0; r < 4; ++r)
                o[r] = (acc[mi][ni][r] + bo[ni]) * mk[r] + xv[r];
            *(f32x4*)(out + ((size_t)n*CC + co)*TT + t) = o;
        }
    }
}

// ---------------- K4: InstanceNorm over T per (n,c), in place ----------------
__global__ __launch_bounds__(256) void inorm(float* __restrict__ out){
    __shared__ float sS[4], sQ2[4];
    float* row = out + (size_t)blockIdx.x * TT;
    f32x4 vbuf[4];
    float s = 0.f, ss = 0.f;
    for (int i = 0; i < 4; ++i){
        f32x4 vv = *(const f32x4*)(row + (size_t)(i*256 + threadIdx.x)*4);
        vbuf[i] = vv;
        for (int r = 0; r < 4; ++r){ s += vv[r]; ss += vv[r]*vv[r]; }
    }
    for (int d = 1; d < 64; d <<= 1){ s += __shfl_xor(s, d); ss += __shfl_xor(ss, d); }
    int w = threadIdx.x >> 6;
    if ((threadIdx.x & 63) == 0){ sS[w] = s; sQ2[w] = ss; }
    __syncthreads();
    s  = sS[0] + sS[1] + sS[2] + sS[3];
    ss = sQ2[0] + sQ2[1] + sQ2[2] + sQ2[3];
    float mean = s * (1.0f/TT);
    float var  = ss * (1.0f/TT) - mean*mean;
    float rstd = rsqrtf(var + 1e-5f);
    for (int i = 0; i < 4; ++i){
        f32x4 vv = vbuf[i], o;
        for (int r = 0; r < 4; ++r) o[r] = (vv[r] - mean) * rstd;
        *(f32x4*)(row + (size_t)(i*256 + threadIdx.x)*4) = o;
    }
}

extern "C" void kernel_launch(void* const* d_in, const int* in_sizes, int n_in,
                              void* d_out, int out_size, void* d_ws, size_t ws_size,
                              hipStream_t stream) {
    const float* x     = (const float*)d_in[0];
    const float* q     = (const float*)d_in[1];
    const float* k     = (const float*)d_in[2];
    const float* v     = (const float*)d_in[3];
    const float* masks = (const float*)d_in[4];
    const float* W_in  = (const float*)d_in[5];
    const float* b_in  = (const float*)d_in[6];
    const float* W_out = (const float*)d_in[7];
    const float* b_out = (const float*)d_in[8];
    float* out = (float*)d_out;

    ushort* ws  = (ushort*)d_ws;
    ushort* XT  = ws;                       // 3*8388608 bf16  (q,k,v transposed)
    ushort* Wb  = ws + (size_t)3*NTC;       // 786432
    ushort* Wob = Wb + 786432;              // 262144
    ushort* P   = Wob + 262144;             // 25165824 (projected qkv, [N*T][1536])
    ushort* ctx = ws;                       // aliases XT (free after proj_gemm)

    cvt_w<<<1024, 256, 0, stream>>>(W_in, W_out, Wb, Wob);
    transpose_cvt<<<6144, 256, 0, stream>>>(q, k, v, XT);
    proj_gemm<<<dim3(12, 128), 256, 0, stream>>>(XT, Wb, b_in, P);
    attn_kernel<<<2048, 256, 0, stream>>>(P, masks, ctx);
    out_gemm<<<dim3(4, 128), 256, 0, stream>>>(ctx, Wob, b_out, x, masks, out);
    inorm<<<2048, 256, 0, stream>>>(out);
}